// Round 1
// baseline (216.713 us; speedup 1.0000x reference)
//
#include <hip/hip_runtime.h>
#include <utility>

// CGA Cl(4,1) sandwich pipeline: out = decode( V * encode(x) * ~V ), per point.
// HBM floor: 88 B/point * 2^21 = 184.5 MB -> ~27 us at achievable BW (6.8 TB/s,
// measured from the harness's own 512MiB poison fills).
//
// R4 change: the R3 kernel was bulk-synchronous -- per 256-point block:
// load -> scatter -> syncthreads (vmcnt(0) drain!) -> compute -> syncthreads ->
// store -> block dies. Memory demand was bursty and the full HBM latency was
// exposed once per tile; est. kernel time ~52.8 us = 3.5 TB/s (52% of peak).
// This version:
//   - persistent blocks: 8 tiles of 256 points per block (grid 1024 = 4/CU
//     exact fill), register-prefetching tile k+1's global loads while tile k
//     computes -> continuous HBM demand, latency paid once per block.
//   - raw `s_waitcnt lgkmcnt(0); s_barrier` instead of __syncthreads: the two
//     barriers only need LDS visibility; NOT draining vmcnt lets the prefetch
//     loads stay in flight across both barriers (waited only by register
//     dependency at the next scatter).
//   - out stored directly from registers (3 scalar dwords, dense 768B/wave
//     range, L2 write-combined) -- drops lds_o and the third barrier.
// Versor LDS transpose (XOR-swizzled, conflict-free) unchanged from R3.

namespace cga {

__host__ __device__ constexpr int popc5(int x) {
    int c = 0;
    for (int i = 0; i < 5; ++i) c += (x >> i) & 1;
    return c;
}
__host__ __device__ constexpr int blade_of_even(int idx) {
    int cnt = 0;
    for (int b = 0; b < 32; ++b)
        if ((popc5(b) & 1) == 0) { if (cnt == idx) return b; ++cnt; }
    return 0;
}
__host__ __device__ constexpr int blade_of_odd(int idx) {
    int cnt = 0;
    for (int b = 0; b < 32; ++b)
        if ((popc5(b) & 1) == 1) { if (cnt == idx) return b; ++cnt; }
    return 0;
}
__host__ __device__ constexpr int even_index(int blade) {
    int idx = 0;
    for (int b = 0; b < blade; ++b) if ((popc5(b) & 1) == 0) ++idx;
    return idx;
}
__host__ __device__ constexpr int odd_index(int blade) {
    int idx = 0;
    for (int b = 0; b < blade; ++b) if ((popc5(b) & 1) == 1) ++idx;
    return idx;
}
__host__ __device__ constexpr int mul_sign(int a, int b) {
    int s = 0;
    for (int t = a >> 1; t; t >>= 1) s += popc5(t & b);
    int sign = (s & 1) ? -1 : 1;
    if ((a & b) & 16) sign = -sign;   // shared e5 squares to -1
    return sign;
}
__host__ __device__ constexpr int rev_sign(int b) {
    int g = popc5(b);
    return ((g * (g - 1) / 2) & 1) ? -1 : 1;
}

struct Tables {
    int t1_dst[16][5];
    int t1_sgn[16][5];
    int t2_e[16][5];
    int t2_sgn[16][5];
};

__host__ __device__ constexpr Tables make_tables() {
    Tables r{};
    for (int ie = 0; ie < 16; ++ie) {
        const int a = blade_of_even(ie);
        for (int ip = 0; ip < 5; ++ip) {
            const int b = 1 << ip;
            const int c = a ^ b;
            r.t1_dst[ie][ip] = odd_index(c);
            r.t1_sgn[ie][ip] = mul_sign(a, b);
        }
    }
    for (int io = 0; io < 16; ++io) {
        const int a = blade_of_odd(io);
        for (int iq = 0; iq < 5; ++iq) {
            const int c = 1 << iq;
            const int b = a ^ c;   // connecting blade: always even grade
            r.t2_e[io][iq]   = even_index(b);
            r.t2_sgn[io][iq] = mul_sign(a, b) * rev_sign(b);
        }
    }
    return r;
}

constexpr Tables TAB = make_tables();

}  // namespace cga

template <int IE, int IP>
__device__ __forceinline__ void t1_term(const float (&v)[16], const float (&p)[5],
                                        float (&mx)[16]) {
    constexpr int dst = cga::TAB.t1_dst[IE][IP];
    constexpr int sgn = cga::TAB.t1_sgn[IE][IP];
    if constexpr (sgn >= 0) mx[dst] = __builtin_fmaf( v[IE], p[IP], mx[dst]);
    else                    mx[dst] = __builtin_fmaf(-v[IE], p[IP], mx[dst]);
}
template <std::size_t... I>
__device__ __forceinline__ void t1_all(const float (&v)[16], const float (&p)[5],
                                       float (&mx)[16], std::index_sequence<I...>) {
    (t1_term<(int)(I / 5), (int)(I % 5)>(v, p, mx), ...);
}
template <int IO, int IQ>
__device__ __forceinline__ void t2_term(const float (&v)[16], const float (&mx)[16],
                                        float (&q)[5]) {
    constexpr int e   = cga::TAB.t2_e[IO][IQ];
    constexpr int sgn = cga::TAB.t2_sgn[IO][IQ];
    if constexpr (sgn >= 0) q[IQ] = __builtin_fmaf( mx[IO], v[e], q[IQ]);
    else                    q[IQ] = __builtin_fmaf(-mx[IO], v[e], q[IQ]);
}
template <std::size_t... I>
__device__ __forceinline__ void t2_all(const float (&v)[16], const float (&mx)[16],
                                       float (&q)[5], std::index_sequence<I...>) {
    (t2_term<(int)(I / 5), (int)(I % 5)>(v, mx, q), ...);
}

__device__ __forceinline__ void cga_compute(const float (&v)[16],
                                            float x0, float x1, float x2,
                                            float& o0, float& o1, float& o2) {
    const float hs = 0.5f * (x0 * x0 + x1 * x1 + x2 * x2);
    const float p[5] = {x0, x1, x2, hs - 0.5f, hs + 0.5f};
    float mx[16] = {};
    t1_all(v, p, mx, std::make_index_sequence<16 * 5>{});
    float q[5] = {};
    t2_all(v, mx, q, std::make_index_sequence<16 * 5>{});
    const float inv = 1.0f / (q[4] - q[3]);
    o0 = q[0] * inv;
    o1 = q[1] * inv;
    o2 = q[2] * inv;
}

// LDS-visibility-only barrier: waits this wave's own ds ops, then block
// barrier. Deliberately does NOT drain vmcnt, so prefetch global loads stay
// in flight across it. "memory" clobber pins LDS ops on their side of it.
#define CGA_BARRIER_LGKM() asm volatile("s_waitcnt lgkmcnt(0)\n\ts_barrier" ::: "memory")

// ---- persistent pipelined kernel: NT tiles of 256 points per 256-thread
// block. Requires n % 256 == 0 (true here: n = 2^21). ----
template <int NT>
__global__ __launch_bounds__(256) void cga_pipe_kernel(
    const float* __restrict__ versor,
    const float* __restrict__ x,
    float* __restrict__ out,
    int total_tiles)
{
    __shared__ float lds_v[16 * 256];  // component-major, XOR-swizzled
    __shared__ float lds_x[3 * 256];

    const int t = threadIdx.x;
    int tile = blockIdx.x * NT;
    const int tile_end = (tile + NT < total_tiles) ? (tile + NT) : total_tiles;

    const float4* vg = reinterpret_cast<const float4*>(versor);
    const float4* xg = reinterpret_cast<const float4*>(x);

    // ---- prologue: load first tile (dense 16 B/lane contiguous) ----
    float4 f[4];
#pragma unroll
    for (int j = 0; j < 4; ++j)
        f[j] = vg[(size_t)tile * 1024 + (size_t)(j * 256 + t)];
    float4 xf = make_float4(0.f, 0.f, 0.f, 0.f);
    if (t < 192)
        xf = xg[(size_t)tile * 192 + t];

    while (tile < tile_end) {
        // ---- scatter versor float4s to component-major LDS ----
        // global float4 (j*256+t) = point p = 64j + t/4, comps c = 4*(t&3)+w.
        // LDS word for (c,p): c*256 + (p ^ (4*(c&7))).  Writes 2-way aliased
        // (free per m136); reads conflict-free.
        {
            const int b = t & 3;
            const int a = t >> 2;
#pragma unroll
            for (int j = 0; j < 4; ++j) {
                const int p = 64 * j + a;
                const float w4[4] = {f[j].x, f[j].y, f[j].z, f[j].w};
#pragma unroll
                for (int w = 0; w < 4; ++w) {
                    const int c = 4 * b + w;
                    lds_v[c * 256 + (p ^ (4 * (c & 7)))] = w4[w];
                }
            }
        }
        if (t < 192)
            reinterpret_cast<float4*>(lds_x)[t] = xf;

        CGA_BARRIER_LGKM();   // A: ds_writes visible to all waves

        // ---- per-thread gather (conflict-free) ----
        float v[16];
#pragma unroll
        for (int c = 0; c < 16; ++c)
            v[c] = lds_v[c * 256 + (t ^ (4 * (c & 7)))];
        const float x0 = lds_x[3 * t + 0];
        const float x1 = lds_x[3 * t + 1];
        const float x2 = lds_x[3 * t + 2];

        // ---- prefetch next tile; these loads cross both barriers and are
        // only waited (via register dep) at the next scatter ----
        const int cur = tile;
        ++tile;
        if (tile < tile_end) {
#pragma unroll
            for (int j = 0; j < 4; ++j)
                f[j] = vg[(size_t)tile * 1024 + (size_t)(j * 256 + t)];
            if (t < 192)
                xf = xg[(size_t)tile * 192 + t];
        }

        CGA_BARRIER_LGKM();   // B: all waves' ds_reads done -> LDS reusable

        // ---- compute + direct store (overlaps with prefetch in flight) ----
        float o0, o1, o2;
        cga_compute(v, x0, x1, x2, o0, o1, o2);
        const size_t base = (size_t)cur * 256 + t;
        out[3 * base + 0] = o0;
        out[3 * base + 1] = o1;
        out[3 * base + 2] = o2;
    }
}

// ---- fallback for n not divisible by 256 (not hit for this problem) ----
__global__ __launch_bounds__(256) void cga_simple_kernel(
    const float* __restrict__ versor,
    const float* __restrict__ x,
    float* __restrict__ out,
    int n)
{
    const int i = blockIdx.x * blockDim.x + threadIdx.x;
    if (i >= n) return;
    const float4* v4 = reinterpret_cast<const float4*>(versor) + (size_t)i * 4;
    const float4 a0 = v4[0], a1 = v4[1], a2 = v4[2], a3 = v4[3];
    const float v[16] = {a0.x, a0.y, a0.z, a0.w, a1.x, a1.y, a1.z, a1.w,
                         a2.x, a2.y, a2.z, a2.w, a3.x, a3.y, a3.z, a3.w};
    float o0, o1, o2;
    cga_compute(v, x[(size_t)3 * i], x[(size_t)3 * i + 1], x[(size_t)3 * i + 2],
                o0, o1, o2);
    out[(size_t)3 * i + 0] = o0;
    out[(size_t)3 * i + 1] = o1;
    out[(size_t)3 * i + 2] = o2;
}

extern "C" void kernel_launch(void* const* d_in, const int* in_sizes, int n_in,
                              void* d_out, int out_size, void* d_ws, size_t ws_size,
                              hipStream_t stream) {
    const float* versor = (const float*)d_in[0];  // (N, 16) fp32
    const float* x      = (const float*)d_in[1];  // (N, 3)  fp32
    float* out          = (float*)d_out;          // (N, 3)  fp32
    const int n = in_sizes[0] / 16;

    if ((n & 255) == 0) {
        const int tiles = n / 256;
        constexpr int NT = 8;   // 8 tiles/block -> 1024 blocks = 4/CU exact fill
        const int grid = (tiles + NT - 1) / NT;
        cga_pipe_kernel<NT><<<grid, 256, 0, stream>>>(versor, x, out, tiles);
    } else {
        cga_simple_kernel<<<(n + 255) / 256, 256, 0, stream>>>(versor, x, out, n);
    }
}

// Round 2
// 211.962 us; speedup vs baseline: 1.0224x; 1.0224x over previous
//
#include <hip/hip_runtime.h>
#include <utility>

// CGA Cl(4,1) sandwich pipeline: out = decode( V * encode(x) * ~V ), per point.
// HBM floor: 88 B/point * 2^21 = 184.5 MB -> ~27-29 us at achievable BW.
//
// R5 change: remove the LDS stage entirely.
// Post-mortem R4: persistent pipelined blocks REGRESSED (52.8 -> ~60 us kernel).
// R3's 7-blocks/CU TLP was already smoothing the barrier phases; pinning 4
// blocks/CU + per-tile barrier lockstep + prefetch register pressure lost more
// than pipelining gained. Revised theory: the gap vs the ~29 us HBM floor is
// the transpose machinery itself (~37 DS ops + 2 block-wide barriers per
// point on every block's critical path), not burstiness.
// This version loads the versor directly as 4 consecutive float4s per lane
// (AoS): each lane gets its own point's 16 components with no transpose at
// all. Per-instruction lane stride is 64 B (wave spans 4 KB, 32 cache lines,
// 1/4 of each line per instruction) -- but all 4 instructions together consume
// every byte, so L1 absorbs the amplification (~512 L1 line-transactions per
// 256 points vs ~2200 cy HBM budget/CU) and HBM traffic is unchanged.
// ILP = 4 points/thread: all 20 loads issued before any compute -> ~4.3 KB
// outstanding per wave, saturating the per-CU BW-latency product (~9 KB)
// even at 4 waves/SIMD. No barriers, no DS, no phase coupling: pure stream.

namespace cga {

__host__ __device__ constexpr int popc5(int x) {
    int c = 0;
    for (int i = 0; i < 5; ++i) c += (x >> i) & 1;
    return c;
}
__host__ __device__ constexpr int blade_of_even(int idx) {
    int cnt = 0;
    for (int b = 0; b < 32; ++b)
        if ((popc5(b) & 1) == 0) { if (cnt == idx) return b; ++cnt; }
    return 0;
}
__host__ __device__ constexpr int blade_of_odd(int idx) {
    int cnt = 0;
    for (int b = 0; b < 32; ++b)
        if ((popc5(b) & 1) == 1) { if (cnt == idx) return b; ++cnt; }
    return 0;
}
__host__ __device__ constexpr int even_index(int blade) {
    int idx = 0;
    for (int b = 0; b < blade; ++b) if ((popc5(b) & 1) == 0) ++idx;
    return idx;
}
__host__ __device__ constexpr int odd_index(int blade) {
    int idx = 0;
    for (int b = 0; b < blade; ++b) if ((popc5(b) & 1) == 1) ++idx;
    return idx;
}
__host__ __device__ constexpr int mul_sign(int a, int b) {
    int s = 0;
    for (int t = a >> 1; t; t >>= 1) s += popc5(t & b);
    int sign = (s & 1) ? -1 : 1;
    if ((a & b) & 16) sign = -sign;   // shared e5 squares to -1
    return sign;
}
__host__ __device__ constexpr int rev_sign(int b) {
    int g = popc5(b);
    return ((g * (g - 1) / 2) & 1) ? -1 : 1;
}

struct Tables {
    int t1_dst[16][5];
    int t1_sgn[16][5];
    int t2_e[16][5];
    int t2_sgn[16][5];
};

__host__ __device__ constexpr Tables make_tables() {
    Tables r{};
    for (int ie = 0; ie < 16; ++ie) {
        const int a = blade_of_even(ie);
        for (int ip = 0; ip < 5; ++ip) {
            const int b = 1 << ip;
            const int c = a ^ b;
            r.t1_dst[ie][ip] = odd_index(c);
            r.t1_sgn[ie][ip] = mul_sign(a, b);
        }
    }
    for (int io = 0; io < 16; ++io) {
        const int a = blade_of_odd(io);
        for (int iq = 0; iq < 5; ++iq) {
            const int c = 1 << iq;
            const int b = a ^ c;   // connecting blade: always even grade
            r.t2_e[io][iq]   = even_index(b);
            r.t2_sgn[io][iq] = mul_sign(a, b) * rev_sign(b);
        }
    }
    return r;
}

constexpr Tables TAB = make_tables();

}  // namespace cga

template <int IE, int IP>
__device__ __forceinline__ void t1_term(const float (&v)[16], const float (&p)[5],
                                        float (&mx)[16]) {
    constexpr int dst = cga::TAB.t1_dst[IE][IP];
    constexpr int sgn = cga::TAB.t1_sgn[IE][IP];
    if constexpr (sgn >= 0) mx[dst] = __builtin_fmaf( v[IE], p[IP], mx[dst]);
    else                    mx[dst] = __builtin_fmaf(-v[IE], p[IP], mx[dst]);
}
template <std::size_t... I>
__device__ __forceinline__ void t1_all(const float (&v)[16], const float (&p)[5],
                                       float (&mx)[16], std::index_sequence<I...>) {
    (t1_term<(int)(I / 5), (int)(I % 5)>(v, p, mx), ...);
}
template <int IO, int IQ>
__device__ __forceinline__ void t2_term(const float (&v)[16], const float (&mx)[16],
                                        float (&q)[5]) {
    constexpr int e   = cga::TAB.t2_e[IO][IQ];
    constexpr int sgn = cga::TAB.t2_sgn[IO][IQ];
    if constexpr (sgn >= 0) q[IQ] = __builtin_fmaf( mx[IO], v[e], q[IQ]);
    else                    q[IQ] = __builtin_fmaf(-mx[IO], v[e], q[IQ]);
}
template <std::size_t... I>
__device__ __forceinline__ void t2_all(const float (&v)[16], const float (&mx)[16],
                                       float (&q)[5], std::index_sequence<I...>) {
    (t2_term<(int)(I / 5), (int)(I % 5)>(v, mx, q), ...);
}

__device__ __forceinline__ void cga_compute(const float (&v)[16],
                                            float x0, float x1, float x2,
                                            float& o0, float& o1, float& o2) {
    const float hs = 0.5f * (x0 * x0 + x1 * x1 + x2 * x2);
    const float p[5] = {x0, x1, x2, hs - 0.5f, hs + 0.5f};
    float mx[16] = {};
    t1_all(v, p, mx, std::make_index_sequence<16 * 5>{});
    float q[5] = {};
    t2_all(v, mx, q, std::make_index_sequence<16 * 5>{});
    const float inv = 1.0f / (q[4] - q[3]);
    o0 = q[0] * inv;
    o1 = q[1] * inv;
    o2 = q[2] * inv;
}

// ---- direct-AoS streaming kernel, PPT points per thread, no LDS/barriers ----
// Requires n % (256*PPT) == 0 (true here: n = 2^21, PPT = 4).
template <int PPT>
__global__ __launch_bounds__(256) void cga_aos_kernel(
    const float* __restrict__ versor,
    const float* __restrict__ x,
    float* __restrict__ out,
    int stride_pts)   // = n / PPT = total threads
{
    const int tid = blockIdx.x * blockDim.x + threadIdx.x;

    // ---- issue ALL loads first: PPT * (4 versor float4 + 3 x dwords) ----
    // Independent addresses; compiler hoists into one load cluster with
    // counted vmcnt waits at first use.
    float4 f[PPT][4];
    float  xv[PPT][3];
#pragma unroll
    for (int k = 0; k < PPT; ++k) {
        const size_t p = (size_t)tid + (size_t)k * stride_pts;
        const float4* vp = reinterpret_cast<const float4*>(versor) + p * 4;
        f[k][0] = vp[0];
        f[k][1] = vp[1];
        f[k][2] = vp[2];
        f[k][3] = vp[3];
        xv[k][0] = x[3 * p + 0];
        xv[k][1] = x[3 * p + 1];
        xv[k][2] = x[3 * p + 2];
    }

    // ---- compute + store, point by point (f[k] dies as k advances) ----
#pragma unroll
    for (int k = 0; k < PPT; ++k) {
        const float v[16] = {f[k][0].x, f[k][0].y, f[k][0].z, f[k][0].w,
                             f[k][1].x, f[k][1].y, f[k][1].z, f[k][1].w,
                             f[k][2].x, f[k][2].y, f[k][2].z, f[k][2].w,
                             f[k][3].x, f[k][3].y, f[k][3].z, f[k][3].w};
        float o0, o1, o2;
        cga_compute(v, xv[k][0], xv[k][1], xv[k][2], o0, o1, o2);
        const size_t p = (size_t)tid + (size_t)k * stride_pts;
        out[3 * p + 0] = o0;
        out[3 * p + 1] = o1;
        out[3 * p + 2] = o2;
    }
}

// ---- fallback for n not divisible by 1024 (not hit for this problem) ----
__global__ __launch_bounds__(256) void cga_simple_kernel(
    const float* __restrict__ versor,
    const float* __restrict__ x,
    float* __restrict__ out,
    int n)
{
    const int i = blockIdx.x * blockDim.x + threadIdx.x;
    if (i >= n) return;
    const float4* v4 = reinterpret_cast<const float4*>(versor) + (size_t)i * 4;
    const float4 a0 = v4[0], a1 = v4[1], a2 = v4[2], a3 = v4[3];
    const float v[16] = {a0.x, a0.y, a0.z, a0.w, a1.x, a1.y, a1.z, a1.w,
                         a2.x, a2.y, a2.z, a2.w, a3.x, a3.y, a3.z, a3.w};
    float o0, o1, o2;
    cga_compute(v, x[(size_t)3 * i], x[(size_t)3 * i + 1], x[(size_t)3 * i + 2],
                o0, o1, o2);
    out[(size_t)3 * i + 0] = o0;
    out[(size_t)3 * i + 1] = o1;
    out[(size_t)3 * i + 2] = o2;
}

extern "C" void kernel_launch(void* const* d_in, const int* in_sizes, int n_in,
                              void* d_out, int out_size, void* d_ws, size_t ws_size,
                              hipStream_t stream) {
    const float* versor = (const float*)d_in[0];  // (N, 16) fp32
    const float* x      = (const float*)d_in[1];  // (N, 3)  fp32
    float* out          = (float*)d_out;          // (N, 3)  fp32
    const int n = in_sizes[0] / 16;

    constexpr int PPT = 4;
    if (n % (256 * PPT) == 0) {
        const int threads_total = n / PPT;        // 2^19 for this problem
        const int grid = threads_total / 256;     // 2048 blocks
        cga_aos_kernel<PPT><<<grid, 256, 0, stream>>>(versor, x, out, threads_total);
    } else {
        cga_simple_kernel<<<(n + 255) / 256, 256, 0, stream>>>(versor, x, out, n);
    }
}